// Round 1
// baseline (710.640 us; speedup 1.0000x reference)
//
#include <hip/hip_runtime.h>

// Problem constants
#define M_TOT 8192      // 4 * 2048
#define K_TOT 4096      // IN_FEATURES
#define N_TOT 4096      // OUT_FEATURES
#define RANK  64
#define SCALING 0.25f

typedef __bf16 bf16x8 __attribute__((ext_vector_type(8)));
typedef float floatx4 __attribute__((ext_vector_type(4)));

static __device__ __forceinline__ unsigned short f32_to_bf16(float f) {
  unsigned int u = __float_as_uint(f);
  u += 0x7FFFu + ((u >> 16) & 1u);   // round-to-nearest-even
  return (unsigned short)(u >> 16);
}

// async global->LDS, 16B per lane. LDS dest must be base + lane*16 contiguous.
static __device__ __forceinline__ void async_ld16(const void* g, void* l) {
  __builtin_amdgcn_global_load_lds(
      (const __attribute__((address_space(1))) unsigned int*)g,
      (__attribute__((address_space(3))) unsigned int*)l, 16, 0, 0);
}

// ---------------- kernel 1: convert x fp32 -> bf16 ----------------
__global__ __launch_bounds__(256) void cvt_x_kernel(const float4* __restrict__ x,
                                                    ushort4* __restrict__ xb) {
  int i = blockIdx.x * 256 + threadIdx.x;   // grid sized exactly: no bounds check
  float4 v = x[i];
  ushort4 o;
  o.x = f32_to_bf16(v.x);
  o.y = f32_to_bf16(v.y);
  o.z = f32_to_bf16(v.z);
  o.w = f32_to_bf16(v.w);
  xb[i] = o;
}

// ---------------- kernel 2: W_eff = bf16(wq*scale + 0.25*B@A) ----------------
// wq: [N_TOT][K_TOT] int32 (harness uploads integer inputs as int32)
// A:  [RANK][K_TOT] fp32,  B: [N_TOT][RANK] fp32
// Weff: [N_TOT][K_TOT] bf16 bits
__global__ __launch_bounds__(256) void build_weff_kernel(
    const int* __restrict__ wq, const float* __restrict__ scale_p,
    const float* __restrict__ A, const float* __restrict__ B,
    unsigned short* __restrict__ Weff) {
  __shared__ float Bs[64][65];   // [o][r], padded (+1) vs 16-way bank conflict
  __shared__ float As[64][65];   // [r][k], padded

  const int tid = threadIdx.x;
  const int o0 = blockIdx.y * 64;
  const int k0 = blockIdx.x * 64;
  const float scale = scale_p[0];

  for (int i = tid; i < 64 * 64; i += 256) {
    int o = i >> 6, r = i & 63;
    Bs[o][r] = B[(size_t)(o0 + o) * RANK + r];
  }
  for (int i = tid; i < 64 * 64; i += 256) {
    int r = i >> 6, kk = i & 63;
    As[r][kk] = A[(size_t)r * K_TOT + k0 + kk];
  }
  __syncthreads();

  const int to = tid >> 4;   // 0..15  -> o sub-block
  const int tk = tid & 15;   // 0..15  -> k sub-block
  float acc[4][4] = {};
#pragma unroll 8
  for (int r = 0; r < RANK; ++r) {
    float bv[4], av[4];
#pragma unroll
    for (int a = 0; a < 4; ++a) bv[a] = Bs[to * 4 + a][r];
#pragma unroll
    for (int b = 0; b < 4; ++b) av[b] = As[r][tk * 4 + b];
#pragma unroll
    for (int a = 0; a < 4; ++a)
#pragma unroll
      for (int b = 0; b < 4; ++b) acc[a][b] += bv[a] * av[b];
  }
#pragma unroll
  for (int a = 0; a < 4; ++a) {
    int o = o0 + to * 4 + a;
#pragma unroll
    for (int b = 0; b < 4; ++b) {
      int k = k0 + tk * 4 + b;
      float w = (float)wq[(size_t)o * K_TOT + k] * scale + SCALING * acc[a][b];
      Weff[(size_t)o * K_TOT + k] = f32_to_bf16(w);
    }
  }
}

// ---------------- kernel 3: main GEMM, out = Xb @ Weff^T ----------------
// m97 structure: 128x128 tile, BK=32, 4 waves in 2x2, each wave 4x4 MFMAs of
// 16x16x32 bf16. Staging via global_load_lds width=16 into un-padded
// [128][32] LDS tiles (wave-uniform base + lane*16 ordering).
__global__ __launch_bounds__(256) void gemm_kernel(
    const unsigned short* __restrict__ Xb,   // [M_TOT][K_TOT] bf16 bits
    const unsigned short* __restrict__ Wb,   // [N_TOT][K_TOT] bf16 bits
    float* __restrict__ out) {               // [M_TOT][N_TOT] fp32
  __shared__ __align__(16) unsigned short As[128 * 32];  // 8 KB
  __shared__ __align__(16) unsigned short Bs[128 * 32];  // 8 KB

  const int tid = threadIdx.x;
  const int lane = tid & 63;
  const int wave = tid >> 6;       // 0..3
  const int wm = wave >> 1;        // 0..1 : wave row within tile
  const int wn = wave & 1;         // 0..1 : wave col within tile

  const int bM = blockIdx.y * 128;
  const int bN = blockIdx.x * 128;

  // staging: thread tid covers LDS bytes [tid*16, tid*16+16)
  //  -> row = tid/4 (32 elems/row), col = (tid%4)*8
  const int sRow = tid >> 2;
  const int sCol = (tid & 3) * 8;
  const unsigned short* xg0 = Xb + (size_t)(bM + sRow) * K_TOT + sCol;
  const unsigned short* xg1 = xg0 + (size_t)64 * K_TOT;
  const unsigned short* wg0 = Wb + (size_t)(bN + sRow) * K_TOT + sCol;
  const unsigned short* wg1 = wg0 + (size_t)64 * K_TOT;
  unsigned short* la0 = As + tid * 8;
  unsigned short* la1 = As + 64 * 32 + tid * 8;
  unsigned short* lb0 = Bs + tid * 8;
  unsigned short* lb1 = Bs + 64 * 32 + tid * 8;

  // LDS fragment base: row = wsub*64 + i*16 + (lane&15), kcol = (lane>>4)*8
  const unsigned short* pa = As + ((wm * 64) + (lane & 15)) * 32 + (lane >> 4) * 8;
  const unsigned short* pb = Bs + ((wn * 64) + (lane & 15)) * 32 + (lane >> 4) * 8;

  floatx4 acc[4][4] = {};

  for (int kt = 0; kt < K_TOT; kt += 32) {
    __syncthreads();   // previous iter's ds_reads done before overwrite
    async_ld16(xg0 + kt, la0);
    async_ld16(xg1 + kt, la1);
    async_ld16(wg0 + kt, lb0);
    async_ld16(wg1 + kt, lb1);
    __syncthreads();   // drains vmcnt: staged tile visible

    bf16x8 af[4], bf[4];
#pragma unroll
    for (int i = 0; i < 4; ++i) af[i] = *(const bf16x8*)(pa + i * 16 * 32);
#pragma unroll
    for (int j = 0; j < 4; ++j) bf[j] = *(const bf16x8*)(pb + j * 16 * 32);
#pragma unroll
    for (int i = 0; i < 4; ++i)
#pragma unroll
      for (int j = 0; j < 4; ++j)
        acc[i][j] = __builtin_amdgcn_mfma_f32_16x16x32_bf16(af[i], bf[j], acc[i][j], 0, 0, 0);
  }

  // epilogue: D element (i,j,reg r) -> row = bM+wm*64+i*16+(lane>>4)*4+r,
  //                                    col = bN+wn*64+j*16+(lane&15)
  const int row0 = bM + wm * 64 + ((lane >> 4) << 2);
  const int col0 = bN + wn * 64 + (lane & 15);
#pragma unroll
  for (int i = 0; i < 4; ++i) {
#pragma unroll
    for (int j = 0; j < 4; ++j) {
#pragma unroll
      for (int r = 0; r < 4; ++r) {
        out[(size_t)(row0 + i * 16 + r) * N_TOT + (col0 + j * 16)] = acc[i][j][r];
      }
    }
  }
}

extern "C" void kernel_launch(void* const* d_in, const int* in_sizes, int n_in,
                              void* d_out, int out_size, void* d_ws, size_t ws_size,
                              hipStream_t stream) {
  const float* x      = (const float*)d_in[0];   // [4,2048,4096] fp32
  const int*   wq     = (const int*)d_in[1];     // [4096,4096] int (int8 values)
  const float* wscale = (const float*)d_in[2];   // [1] fp32
  const float* lora_A = (const float*)d_in[3];   // [64,4096] fp32
  const float* lora_B = (const float*)d_in[4];   // [4096,64] fp32
  float* out = (float*)d_out;

  // workspace layout: xb (64 MB) | weff (32 MB)
  unsigned short* xb   = (unsigned short*)d_ws;
  unsigned short* weff = (unsigned short*)((char*)d_ws + (size_t)M_TOT * K_TOT * 2);

  // 1. x -> bf16 (8192*4096/4 float4 elements = 8388608 -> 32768 blocks exact)
  cvt_x_kernel<<<32768, 256, 0, stream>>>((const float4*)x, (ushort4*)xb);

  // 2. fold LoRA + dequant into bf16 W_eff
  build_weff_kernel<<<dim3(K_TOT / 64, N_TOT / 64), 256, 0, stream>>>(
      wq, wscale, lora_A, lora_B, weff);

  // 3. main GEMM
  gemm_kernel<<<dim3(N_TOT / 128, M_TOT / 128), 256, 0, stream>>>(xb, weff, out);
}

// Round 2
// 596.349 us; speedup vs baseline: 1.1917x; 1.1917x over previous
//
#include <hip/hip_runtime.h>

// Problem constants
#define M_TOT 8192      // 4 * 2048
#define K_TOT 4096      // IN_FEATURES
#define N_TOT 4096      // OUT_FEATURES
#define RANK  64
#define SCALING 0.25f

typedef __bf16 bf16x8 __attribute__((ext_vector_type(8)));
typedef float floatx4 __attribute__((ext_vector_type(4)));

static __device__ __forceinline__ unsigned short f32_to_bf16(float f) {
  unsigned int u = __float_as_uint(f);
  u += 0x7FFFu + ((u >> 16) & 1u);   // round-to-nearest-even
  return (unsigned short)(u >> 16);
}

// async global->LDS, 16B per lane. LDS dest must be base + lane*16 contiguous.
static __device__ __forceinline__ void async_ld16(const void* g, void* l) {
  __builtin_amdgcn_global_load_lds(
      (const __attribute__((address_space(1))) unsigned int*)g,
      (__attribute__((address_space(3))) unsigned int*)l, 16, 0, 0);
}

// ---------------- kernel 1: convert x fp32 -> bf16 ----------------
__global__ __launch_bounds__(256) void cvt_x_kernel(const float4* __restrict__ x,
                                                    ushort4* __restrict__ xb) {
  int i = blockIdx.x * 256 + threadIdx.x;   // grid sized exactly: no bounds check
  float4 v = x[i];
  ushort4 o;
  o.x = f32_to_bf16(v.x);
  o.y = f32_to_bf16(v.y);
  o.z = f32_to_bf16(v.z);
  o.w = f32_to_bf16(v.w);
  xb[i] = o;
}

// ---------------- kernel 2: W_eff = bf16(wq*scale + 0.25*B@A) ----------------
// wq: [N_TOT][K_TOT] int32, A: [RANK][K_TOT] fp32, B: [N_TOT][RANK] fp32
// Weff: [N_TOT][K_TOT] bf16 bits
// R1 fix: wq loads as int4 (fully coalesced: 16 lanes x 16B contiguous per
// row-group), Weff stores as ushort4 (8B, contiguous) — was 16 scalar loads +
// 16 scalar 2B stores at ~25% efficiency.
__global__ __launch_bounds__(256) void build_weff_kernel(
    const int* __restrict__ wq, const float* __restrict__ scale_p,
    const float* __restrict__ A, const float* __restrict__ B,
    unsigned short* __restrict__ Weff) {
  __shared__ float Bs[64][65];   // [o][r], padded
  __shared__ float As[64][65];   // [r][k], padded

  const int tid = threadIdx.x;
  const int o0 = blockIdx.y * 64;
  const int k0 = blockIdx.x * 64;
  const float scale = scale_p[0];

  for (int i = tid; i < 64 * 64; i += 256) {
    int o = i >> 6, r = i & 63;
    Bs[o][r] = B[(size_t)(o0 + o) * RANK + r];
  }
  for (int i = tid; i < 64 * 64; i += 256) {
    int r = i >> 6, kk = i & 63;
    As[r][kk] = A[(size_t)r * K_TOT + k0 + kk];
  }
  __syncthreads();

  const int to = tid >> 4;   // 0..15 -> o sub-block (4 rows)
  const int tk = tid & 15;   // 0..15 -> k sub-block (4 contiguous cols)
  float acc[4][4] = {};
#pragma unroll 8
  for (int r = 0; r < RANK; ++r) {
    float bv[4], av[4];
#pragma unroll
    for (int a = 0; a < 4; ++a) bv[a] = Bs[to * 4 + a][r];
#pragma unroll
    for (int b = 0; b < 4; ++b) av[b] = As[r][tk * 4 + b];
#pragma unroll
    for (int a = 0; a < 4; ++a)
#pragma unroll
      for (int b = 0; b < 4; ++b) acc[a][b] += bv[a] * av[b];
  }
#pragma unroll
  for (int a = 0; a < 4; ++a) {
    const int o = o0 + to * 4 + a;
    const size_t base = (size_t)o * K_TOT + k0 + tk * 4;
    const int4 wv = *(const int4*)(wq + base);
    ushort4 st;
    st.x = f32_to_bf16((float)wv.x * scale + SCALING * acc[a][0]);
    st.y = f32_to_bf16((float)wv.y * scale + SCALING * acc[a][1]);
    st.z = f32_to_bf16((float)wv.z * scale + SCALING * acc[a][2]);
    st.w = f32_to_bf16((float)wv.w * scale + SCALING * acc[a][3]);
    *(ushort4*)(Weff + base) = st;
  }
}

// ---------------- kernel 3: main GEMM, out = Xb @ Weff^T ----------------
// R1 fix: BK=64 as two concatenated BK=32 sub-tiles. Row stride stays 64B
// (2-way LDS aliasing = free), global_load_lds layout stays legal, barriers
// halve (64 iters), 32 MFMAs per barrier pair. LDS = 32 KB.
__global__ __launch_bounds__(256) void gemm_kernel(
    const unsigned short* __restrict__ Xb,   // [M_TOT][K_TOT] bf16 bits
    const unsigned short* __restrict__ Wb,   // [N_TOT][K_TOT] bf16 bits
    float* __restrict__ out) {               // [M_TOT][N_TOT] fp32
  __shared__ __align__(16) unsigned short As[2 * 128 * 32];  // 16 KB
  __shared__ __align__(16) unsigned short Bs[2 * 128 * 32];  // 16 KB

  const int tid = threadIdx.x;
  const int lane = tid & 63;
  const int wave = tid >> 6;       // 0..3
  const int wm = wave >> 1;        // 0..1
  const int wn = wave & 1;         // 0..1

  const int bM = blockIdx.y * 128;
  const int bN = blockIdx.x * 128;

  // staging: thread tid covers 16B: row = tid/4 (32 elems/row), col=(tid%4)*8
  const int sRow = tid >> 2;
  const int sCol = (tid & 3) * 8;
  const unsigned short* xg0 = Xb + (size_t)(bM + sRow) * K_TOT + sCol;
  const unsigned short* xg1 = xg0 + (size_t)64 * K_TOT;
  const unsigned short* wg0 = Wb + (size_t)(bN + sRow) * K_TOT + sCol;
  const unsigned short* wg1 = wg0 + (size_t)64 * K_TOT;
  unsigned short* la00 = As + tid * 8;               // rows 0..63,  k 0..31
  unsigned short* la01 = As + 64 * 32 + tid * 8;     // rows 64..127, k 0..31
  unsigned short* la10 = As + 128 * 32 + tid * 8;    // rows 0..63,  k 32..63
  unsigned short* la11 = As + 128 * 32 + 64 * 32 + tid * 8;
  unsigned short* lb00 = Bs + tid * 8;
  unsigned short* lb01 = Bs + 64 * 32 + tid * 8;
  unsigned short* lb10 = Bs + 128 * 32 + tid * 8;
  unsigned short* lb11 = Bs + 128 * 32 + 64 * 32 + tid * 8;

  // LDS fragment base: row = wm*64 + i*16 + (lane&15), kcol = (lane>>4)*8
  const unsigned short* pa = As + ((wm * 64) + (lane & 15)) * 32 + (lane >> 4) * 8;
  const unsigned short* pb = Bs + ((wn * 64) + (lane & 15)) * 32 + (lane >> 4) * 8;

  floatx4 acc[4][4] = {};

  for (int kt = 0; kt < K_TOT; kt += 64) {
    __syncthreads();   // previous iter's ds_reads done before overwrite
    async_ld16(xg0 + kt, la00);
    async_ld16(xg1 + kt, la01);
    async_ld16(xg0 + kt + 32, la10);
    async_ld16(xg1 + kt + 32, la11);
    async_ld16(wg0 + kt, lb00);
    async_ld16(wg1 + kt, lb01);
    async_ld16(wg0 + kt + 32, lb10);
    async_ld16(wg1 + kt + 32, lb11);
    __syncthreads();   // drains vmcnt: staged tiles visible

#pragma unroll
    for (int ks = 0; ks < 2; ++ks) {
      const unsigned short* pak = pa + ks * 128 * 32;
      const unsigned short* pbk = pb + ks * 128 * 32;
      bf16x8 af[4], bf[4];
#pragma unroll
      for (int i = 0; i < 4; ++i) af[i] = *(const bf16x8*)(pak + i * 16 * 32);
#pragma unroll
      for (int j = 0; j < 4; ++j) bf[j] = *(const bf16x8*)(pbk + j * 16 * 32);
#pragma unroll
      for (int i = 0; i < 4; ++i)
#pragma unroll
        for (int j = 0; j < 4; ++j)
          acc[i][j] = __builtin_amdgcn_mfma_f32_16x16x32_bf16(af[i], bf[j], acc[i][j], 0, 0, 0);
    }
  }

  // epilogue: D(i,j,r) -> row = bM+wm*64+i*16+(lane>>4)*4+r, col = bN+wn*64+j*16+(lane&15)
  const int row0 = bM + wm * 64 + ((lane >> 4) << 2);
  const int col0 = bN + wn * 64 + (lane & 15);
#pragma unroll
  for (int i = 0; i < 4; ++i) {
#pragma unroll
    for (int j = 0; j < 4; ++j) {
#pragma unroll
      for (int r = 0; r < 4; ++r) {
        out[(size_t)(row0 + i * 16 + r) * N_TOT + (col0 + j * 16)] = acc[i][j][r];
      }
    }
  }
}

extern "C" void kernel_launch(void* const* d_in, const int* in_sizes, int n_in,
                              void* d_out, int out_size, void* d_ws, size_t ws_size,
                              hipStream_t stream) {
  const float* x      = (const float*)d_in[0];   // [4,2048,4096] fp32
  const int*   wq     = (const int*)d_in[1];     // [4096,4096] int
  const float* wscale = (const float*)d_in[2];   // [1] fp32
  const float* lora_A = (const float*)d_in[3];   // [64,4096] fp32
  const float* lora_B = (const float*)d_in[4];   // [4096,64] fp32
  float* out = (float*)d_out;

  unsigned short* xb   = (unsigned short*)d_ws;
  unsigned short* weff = (unsigned short*)((char*)d_ws + (size_t)M_TOT * K_TOT * 2);

  cvt_x_kernel<<<32768, 256, 0, stream>>>((const float4*)x, (ushort4*)xb);
  build_weff_kernel<<<dim3(K_TOT / 64, N_TOT / 64), 256, 0, stream>>>(
      wq, wscale, lora_A, lora_B, weff);
  gemm_kernel<<<dim3(N_TOT / 128, M_TOT / 128), 256, 0, stream>>>(xb, weff, out);
}